// Round 1
// baseline (366.628 us; speedup 1.0000x reference)
//
#include <hip/hip_runtime.h>
#include <hip/hip_bf16.h>

// Problem constants (B=4, S=2048, D=512, H=8, Dh=64)
#define BATCH 4
#define SEQ   2048
#define DIM   512
#define NH    8
#define DH    64
#define NTOK  (BATCH*SEQ)        // 8192

typedef __bf16 bf16x8 __attribute__((ext_vector_type(8)));
typedef float  f32x4  __attribute__((ext_vector_type(4)));

#define MFMA16(a,b,c) __builtin_amdgcn_mfma_f32_16x16x32_bf16((a),(b),(c),0,0,0)

// ---------------------------------------------------------------------------
// fp32 -> bf16 convert, 8 elems/thread
// ---------------------------------------------------------------------------
__global__ __launch_bounds__(256) void cvt_f32_bf16(const float* __restrict__ src,
                                                    __bf16* __restrict__ dst, int n8) {
  int i = blockIdx.x * blockDim.x + threadIdx.x;
  if (i >= n8) return;
  const float4* s = (const float4*)src;
  float4 a = s[2*i], b = s[2*i+1];
  bf16x8 o;
  o[0] = (__bf16)a.x; o[1] = (__bf16)a.y; o[2] = (__bf16)a.z; o[3] = (__bf16)a.w;
  o[4] = (__bf16)b.x; o[5] = (__bf16)b.y; o[6] = (__bf16)b.z; o[7] = (__bf16)b.w;
  *(bf16x8*)&dst[8*i] = o;
}

// ---------------------------------------------------------------------------
// NT GEMM 128x128 tile: C[i,j] = sum_k A[i,k]*W[j,k] + bias[j]
// z = 0/1/2 -> Q / K / V projection; Q,K stored [B,H,S,Dh]; V stored [B,H,Dh,S]
// ---------------------------------------------------------------------------
__global__ __launch_bounds__(256) void gemm_qkv(
    const __bf16* __restrict__ xb,
    const __bf16* __restrict__ wq, const __bf16* __restrict__ wk,
    const __bf16* __restrict__ wv,
    const float* __restrict__ bq, const float* __restrict__ bk,
    const float* __restrict__ bv,
    __bf16* __restrict__ Qb, __bf16* __restrict__ Kb, __bf16* __restrict__ Vt)
{
  const int z = blockIdx.z;
  const __bf16* W    = (z == 0) ? wq : (z == 1) ? wk : wv;
  const float*  bias = (z == 0) ? bq : (z == 1) ? bk : bv;

  __shared__ __bf16 As[128*72];   // +8 pad: 2-way LDS conflict only (free)
  __shared__ __bf16 Bs[128*72];

  const int tid  = threadIdx.x;
  const int m0   = blockIdx.x * 128, n0 = blockIdx.y * 128;
  const int w    = tid >> 6, lane = tid & 63, quad = lane >> 4, l16 = lane & 15;
  const int wm   = (w >> 1) * 64, wn = (w & 1) * 64;

  f32x4 acc[4][4] = {};

  for (int k0 = 0; k0 < DIM; k0 += 64) {
#pragma unroll
    for (int i = 0; i < 4; ++i) {
      int c   = tid + i * 256;       // 1024 chunks of 8 bf16
      int row = c >> 3;
      int kc  = (c & 7) << 3;
      *(bf16x8*)&As[row*72 + kc] = *(const bf16x8*)&xb[(size_t)(m0+row)*DIM + k0 + kc];
      *(bf16x8*)&Bs[row*72 + kc] = *(const bf16x8*)&W [(size_t)(n0+row)*DIM + k0 + kc];
    }
    __syncthreads();
#pragma unroll
    for (int kk = 0; kk < 2; ++kk) {
      const int ko = kk*32 + quad*8;
      bf16x8 af[4], bfr[4];
#pragma unroll
      for (int f = 0; f < 4; ++f) {
        af[f]  = *(const bf16x8*)&As[(wm + f*16 + l16)*72 + ko];
        bfr[f] = *(const bf16x8*)&Bs[(wn + f*16 + l16)*72 + ko];
      }
#pragma unroll
      for (int fm = 0; fm < 4; ++fm)
#pragma unroll
        for (int fn = 0; fn < 4; ++fn)
          acc[fm][fn] = MFMA16(af[fm], bfr[fn], acc[fm][fn]);
    }
    __syncthreads();
  }

  // epilogue: C row = m0+wm+fm*16+quad*4+r ; col = n0+wn+fn*16+l16
#pragma unroll
  for (int fm = 0; fm < 4; ++fm) {
#pragma unroll
    for (int fn = 0; fn < 4; ++fn) {
      const int col  = n0 + wn + fn*16 + l16;
      const float bc = bias[col];
      const int h = col >> 6, dh = col & 63;
#pragma unroll
      for (int r = 0; r < 4; ++r) {
        const int row = m0 + wm + fm*16 + quad*4 + r;
        const int b = row >> 11, s = row & 2047;
        const float v = acc[fm][fn][r] + bc;
        if (z == 2) {
          Vt[((size_t)(b*NH + h)*DH + dh)*SEQ + s] = (__bf16)v;
        } else {
          __bf16* O = (z == 0) ? Qb : Kb;
          O[((size_t)(b*NH + h)*SEQ + s)*DH + dh] = (__bf16)v;
        }
      }
    }
  }
}

// ---------------------------------------------------------------------------
// Output projection: out[i,j] = sum_k attn[i,k]*Wo[j,k] + bo[j]  (fp32 out)
// ---------------------------------------------------------------------------
__global__ __launch_bounds__(256) void gemm_out(
    const __bf16* __restrict__ attnb, const __bf16* __restrict__ wo,
    const float* __restrict__ bo, float* __restrict__ out)
{
  __shared__ __bf16 As[128*72];
  __shared__ __bf16 Bs[128*72];

  const int tid = threadIdx.x;
  const int m0  = blockIdx.x * 128, n0 = blockIdx.y * 128;
  const int w   = tid >> 6, lane = tid & 63, quad = lane >> 4, l16 = lane & 15;
  const int wm  = (w >> 1) * 64, wn = (w & 1) * 64;

  f32x4 acc[4][4] = {};

  for (int k0 = 0; k0 < DIM; k0 += 64) {
#pragma unroll
    for (int i = 0; i < 4; ++i) {
      int c   = tid + i * 256;
      int row = c >> 3;
      int kc  = (c & 7) << 3;
      *(bf16x8*)&As[row*72 + kc] = *(const bf16x8*)&attnb[(size_t)(m0+row)*DIM + k0 + kc];
      *(bf16x8*)&Bs[row*72 + kc] = *(const bf16x8*)&wo   [(size_t)(n0+row)*DIM + k0 + kc];
    }
    __syncthreads();
#pragma unroll
    for (int kk = 0; kk < 2; ++kk) {
      const int ko = kk*32 + quad*8;
      bf16x8 af[4], bfr[4];
#pragma unroll
      for (int f = 0; f < 4; ++f) {
        af[f]  = *(const bf16x8*)&As[(wm + f*16 + l16)*72 + ko];
        bfr[f] = *(const bf16x8*)&Bs[(wn + f*16 + l16)*72 + ko];
      }
#pragma unroll
      for (int fm = 0; fm < 4; ++fm)
#pragma unroll
        for (int fn = 0; fn < 4; ++fn)
          acc[fm][fn] = MFMA16(af[fm], bfr[fn], acc[fm][fn]);
    }
    __syncthreads();
  }

#pragma unroll
  for (int fm = 0; fm < 4; ++fm) {
#pragma unroll
    for (int fn = 0; fn < 4; ++fn) {
      const int col  = n0 + wn + fn*16 + l16;
      const float bc = bo[col];
#pragma unroll
      for (int r = 0; r < 4; ++r) {
        const int row = m0 + wm + fm*16 + quad*4 + r;
        out[(size_t)row*DIM + col] = acc[fm][fn][r] + bc;
      }
    }
  }
}

// ---------------------------------------------------------------------------
// Flash attention: grid (S/64, B*H); 4 waves/block, 16 q-rows/wave,
// 32-key tiles, online softmax, P via per-wave LDS (C-layout -> A-layout).
// Waves are fully independent: no __syncthreads in the causal loop.
// ---------------------------------------------------------------------------
__global__ __launch_bounds__(256) void flash_attn(
    const __bf16* __restrict__ Qb, const __bf16* __restrict__ Kb,
    const __bf16* __restrict__ Vt, __bf16* __restrict__ attnb)
{
  const int bh = blockIdx.y;
  const int b  = bh >> 3, h = bh & 7;
  const int tid = threadIdx.x;
  const int w   = tid >> 6, lane = tid & 63, quad = lane >> 4, l16 = lane & 15;
  const int q0  = blockIdx.x * 64 + w * 16;

  const __bf16* Qp = Qb + (size_t)bh * SEQ * DH;   // [s][dh]
  const __bf16* Kp = Kb + (size_t)bh * SEQ * DH;   // [s][dh]
  const __bf16* Vp = Vt + (size_t)bh * DH * SEQ;   // [dh][s]

  __shared__ __bf16 Plds[4][16*40];                // stride 40: 2-way conflicts only
  __bf16* Pw = Plds[w];

  bf16x8 qf[2];
#pragma unroll
  for (int kk = 0; kk < 2; ++kk)
    qf[kk] = *(const bf16x8*)&Qp[(size_t)(q0 + l16)*DH + kk*32 + quad*8];

  f32x4 of[4] = {};
  float mrow[4] = {-1e30f, -1e30f, -1e30f, -1e30f};
  float lrow[4] = {};

  const int ktiles = (q0 + 15) / 32 + 1;           // causal bound for this wave
  for (int kt = 0; kt < ktiles; ++kt) {
    const int k0 = kt * 32;
    // S = Q K^T  (two 16-col fragments covering 32 keys)
    f32x4 sf[2] = {};
#pragma unroll
    for (int fn = 0; fn < 2; ++fn)
#pragma unroll
      for (int kk = 0; kk < 2; ++kk) {
        bf16x8 kf = *(const bf16x8*)&Kp[(size_t)(k0 + fn*16 + l16)*DH + kk*32 + quad*8];
        sf[fn] = MFMA16(qf[kk], kf, sf[fn]);
      }
    // scale + causal mask
    float p[2][4];
#pragma unroll
    for (int fn = 0; fn < 2; ++fn) {
      const int col = k0 + fn*16 + l16;
#pragma unroll
      for (int r = 0; r < 4; ++r) {
        float v = sf[fn][r] * 0.125f;
        const int row = q0 + quad*4 + r;
        if (col > row) v = -1e30f;
        p[fn][r] = v;
      }
    }
    // row max across 16 lanes of this quad-group
    float rmax[4];
#pragma unroll
    for (int r = 0; r < 4; ++r) rmax[r] = fmaxf(p[0][r], p[1][r]);
#pragma unroll
    for (int d = 1; d < 16; d <<= 1)
#pragma unroll
      for (int r = 0; r < 4; ++r)
        rmax[r] = fmaxf(rmax[r], __shfl_xor(rmax[r], d));
    float alpha[4];
#pragma unroll
    for (int r = 0; r < 4; ++r) {
      const float mn = fmaxf(mrow[r], rmax[r]);
      alpha[r] = __expf(mrow[r] - mn);
      mrow[r]  = mn;
    }
#pragma unroll
    for (int fn = 0; fn < 2; ++fn)
#pragma unroll
      for (int r = 0; r < 4; ++r)
        p[fn][r] = __expf(p[fn][r] - mrow[r]);
    float rsum[4];
#pragma unroll
    for (int r = 0; r < 4; ++r) rsum[r] = p[0][r] + p[1][r];
#pragma unroll
    for (int d = 1; d < 16; d <<= 1)
#pragma unroll
      for (int r = 0; r < 4; ++r)
        rsum[r] += __shfl_xor(rsum[r], d);
#pragma unroll
    for (int r = 0; r < 4; ++r)
      lrow[r] = lrow[r] * alpha[r] + rsum[r];
    // rescale O
#pragma unroll
    for (int nd = 0; nd < 4; ++nd)
#pragma unroll
      for (int r = 0; r < 4; ++r)
        of[nd][r] *= alpha[r];
    // P: C-layout -> LDS -> A-layout (same-wave RAW, compiler inserts lgkmcnt)
#pragma unroll
    for (int fn = 0; fn < 2; ++fn)
#pragma unroll
      for (int r = 0; r < 4; ++r)
        Pw[(quad*4 + r)*40 + fn*16 + l16] = (__bf16)p[fn][r];
    bf16x8 pa = *(const bf16x8*)&Pw[l16*40 + quad*8];
    // O += P V   (V^T layout: contiguous in key index)
#pragma unroll
    for (int nd = 0; nd < 4; ++nd) {
      bf16x8 vf = *(const bf16x8*)&Vp[(size_t)(nd*16 + l16)*SEQ + k0 + quad*8];
      of[nd] = MFMA16(pa, vf, of[nd]);
    }
  }

  // normalize + store merged-head layout [B, S, H*Dh]
#pragma unroll
  for (int r = 0; r < 4; ++r) lrow[r] = 1.0f / lrow[r];
#pragma unroll
  for (int nd = 0; nd < 4; ++nd) {
    const int dh = nd*16 + l16;
#pragma unroll
    for (int r = 0; r < 4; ++r) {
      const int q = q0 + quad*4 + r;
      attnb[((size_t)b*SEQ + q)*DIM + h*DH + dh] = (__bf16)(of[nd][r] * lrow[r]);
    }
  }
}

// ---------------------------------------------------------------------------
extern "C" void kernel_launch(void* const* d_in, const int* in_sizes, int n_in,
                              void* d_out, int out_size, void* d_ws, size_t ws_size,
                              hipStream_t stream) {
  const float* x  = (const float*)d_in[0];
  // d_in[1] = causal mask, unused (causality computed analytically)
  const float* Wq = (const float*)d_in[2];
  const float* bq = (const float*)d_in[3];
  const float* Wk = (const float*)d_in[4];
  const float* bk = (const float*)d_in[5];
  const float* Wv = (const float*)d_in[6];
  const float* bv = (const float*)d_in[7];
  const float* Wo = (const float*)d_in[8];
  const float* bo = (const float*)d_in[9];
  float* out = (float*)d_out;

  // workspace carve-up (bf16 elements), total ~44 MB
  __bf16* xb    = (__bf16*)d_ws;
  __bf16* wq    = xb + (size_t)NTOK*DIM;      // 4,194,304
  __bf16* wk    = wq + DIM*DIM;               // +262,144 each
  __bf16* wv    = wk + DIM*DIM;
  __bf16* wo    = wv + DIM*DIM;
  __bf16* Qb    = wo + DIM*DIM;
  __bf16* Kb    = Qb + (size_t)NTOK*DIM;
  __bf16* Vt    = Kb + (size_t)NTOK*DIM;
  __bf16* attnb = Vt + (size_t)NTOK*DIM;

  // converts
  cvt_f32_bf16<<<(NTOK*DIM/8)/256, 256, 0, stream>>>(x,  xb, NTOK*DIM/8);
  cvt_f32_bf16<<<(DIM*DIM/8)/256,  256, 0, stream>>>(Wq, wq, DIM*DIM/8);
  cvt_f32_bf16<<<(DIM*DIM/8)/256,  256, 0, stream>>>(Wk, wk, DIM*DIM/8);
  cvt_f32_bf16<<<(DIM*DIM/8)/256,  256, 0, stream>>>(Wv, wv, DIM*DIM/8);
  cvt_f32_bf16<<<(DIM*DIM/8)/256,  256, 0, stream>>>(Wo, wo, DIM*DIM/8);

  // Q/K/V projections
  gemm_qkv<<<dim3(NTOK/128, DIM/128, 3), 256, 0, stream>>>(
      xb, wq, wk, wv, bq, bk, bv, Qb, Kb, Vt);

  // flash attention
  flash_attn<<<dim3(SEQ/64, BATCH*NH), 256, 0, stream>>>(Qb, Kb, Vt, attnb);

  // output projection
  gemm_out<<<dim3(NTOK/128, DIM/128), 256, 0, stream>>>(attnb, wo, bo, out);
}

// Round 2
// 260.421 us; speedup vs baseline: 1.4078x; 1.4078x over previous
//
#include <hip/hip_runtime.h>
#include <hip/hip_bf16.h>

// Problem constants (B=4, S=2048, D=512, H=8, Dh=64)
#define BATCH 4
#define SEQ   2048
#define DIM   512
#define NH    8
#define DH    64
#define NTOK  (BATCH*SEQ)        // 8192

typedef __bf16 bf16x8 __attribute__((ext_vector_type(8)));
typedef float  f32x4  __attribute__((ext_vector_type(4)));

#define MFMA16(a,b,c) __builtin_amdgcn_mfma_f32_16x16x32_bf16((a),(b),(c),0,0,0)

// ---------------------------------------------------------------------------
// fp32 -> bf16 convert, 8 elems/thread
// ---------------------------------------------------------------------------
__global__ __launch_bounds__(256) void cvt_f32_bf16(const float* __restrict__ src,
                                                    __bf16* __restrict__ dst, int n8) {
  int i = blockIdx.x * blockDim.x + threadIdx.x;
  if (i >= n8) return;
  const float4* s = (const float4*)src;
  float4 a = s[2*i], b = s[2*i+1];
  bf16x8 o;
  o[0] = (__bf16)a.x; o[1] = (__bf16)a.y; o[2] = (__bf16)a.z; o[3] = (__bf16)a.w;
  o[4] = (__bf16)b.x; o[5] = (__bf16)b.y; o[6] = (__bf16)b.z; o[7] = (__bf16)b.w;
  *(bf16x8*)&dst[8*i] = o;
}

// ---------------------------------------------------------------------------
// NT GEMM 128x128 tile: C[i,j] = sum_k A[i,k]*W[j,k] + bias[j]
// z = 0/1/2 -> Q / K / V projection; Q,K stored [B,H,S,Dh]; V stored [B,H,Dh,S]
// ---------------------------------------------------------------------------
__global__ __launch_bounds__(256) void gemm_qkv(
    const __bf16* __restrict__ xb,
    const __bf16* __restrict__ wq, const __bf16* __restrict__ wk,
    const __bf16* __restrict__ wv,
    const float* __restrict__ bq, const float* __restrict__ bk,
    const float* __restrict__ bv,
    __bf16* __restrict__ Qb, __bf16* __restrict__ Kb, __bf16* __restrict__ Vt)
{
  const int z = blockIdx.z;
  const __bf16* W    = (z == 0) ? wq : (z == 1) ? wk : wv;
  const float*  bias = (z == 0) ? bq : (z == 1) ? bk : bv;

  __shared__ __bf16 As[128*72];   // +8 pad: 2-way LDS conflict only (free)
  __shared__ __bf16 Bs[128*72];

  const int tid  = threadIdx.x;
  const int m0   = blockIdx.x * 128, n0 = blockIdx.y * 128;
  const int w    = tid >> 6, lane = tid & 63, quad = lane >> 4, l16 = lane & 15;
  const int wm   = (w >> 1) * 64, wn = (w & 1) * 64;

  f32x4 acc[4][4] = {};

  for (int k0 = 0; k0 < DIM; k0 += 64) {
#pragma unroll
    for (int i = 0; i < 4; ++i) {
      int c   = tid + i * 256;       // 1024 chunks of 8 bf16
      int row = c >> 3;
      int kc  = (c & 7) << 3;
      *(bf16x8*)&As[row*72 + kc] = *(const bf16x8*)&xb[(size_t)(m0+row)*DIM + k0 + kc];
      *(bf16x8*)&Bs[row*72 + kc] = *(const bf16x8*)&W [(size_t)(n0+row)*DIM + k0 + kc];
    }
    __syncthreads();
#pragma unroll
    for (int kk = 0; kk < 2; ++kk) {
      const int ko = kk*32 + quad*8;
      bf16x8 af[4], bfr[4];
#pragma unroll
      for (int f = 0; f < 4; ++f) {
        af[f]  = *(const bf16x8*)&As[(wm + f*16 + l16)*72 + ko];
        bfr[f] = *(const bf16x8*)&Bs[(wn + f*16 + l16)*72 + ko];
      }
#pragma unroll
      for (int fm = 0; fm < 4; ++fm)
#pragma unroll
        for (int fn = 0; fn < 4; ++fn)
          acc[fm][fn] = MFMA16(af[fm], bfr[fn], acc[fm][fn]);
    }
    __syncthreads();
  }

  // epilogue: C row = m0+wm+fm*16+quad*4+r ; col = n0+wn+fn*16+l16
#pragma unroll
  for (int fm = 0; fm < 4; ++fm) {
#pragma unroll
    for (int fn = 0; fn < 4; ++fn) {
      const int col  = n0 + wn + fn*16 + l16;
      const float bc = bias[col];
      const int h = col >> 6, dh = col & 63;
#pragma unroll
      for (int r = 0; r < 4; ++r) {
        const int row = m0 + wm + fm*16 + quad*4 + r;
        const int b = row >> 11, s = row & 2047;
        const float v = acc[fm][fn][r] + bc;
        if (z == 2) {
          Vt[((size_t)(b*NH + h)*DH + dh)*SEQ + s] = (__bf16)v;
        } else {
          __bf16* O = (z == 0) ? Qb : Kb;
          O[((size_t)(b*NH + h)*SEQ + s)*DH + dh] = (__bf16)v;
        }
      }
    }
  }
}

// ---------------------------------------------------------------------------
// Output projection: out[i,j] = sum_k attn[i,k]*Wo[j,k] + bo[j]  (fp32 out)
// ---------------------------------------------------------------------------
__global__ __launch_bounds__(256) void gemm_out(
    const __bf16* __restrict__ attnb, const __bf16* __restrict__ wo,
    const float* __restrict__ bo, float* __restrict__ out)
{
  __shared__ __bf16 As[128*72];
  __shared__ __bf16 Bs[128*72];

  const int tid = threadIdx.x;
  const int m0  = blockIdx.x * 128, n0 = blockIdx.y * 128;
  const int w   = tid >> 6, lane = tid & 63, quad = lane >> 4, l16 = lane & 15;
  const int wm  = (w >> 1) * 64, wn = (w & 1) * 64;

  f32x4 acc[4][4] = {};

  for (int k0 = 0; k0 < DIM; k0 += 64) {
#pragma unroll
    for (int i = 0; i < 4; ++i) {
      int c   = tid + i * 256;
      int row = c >> 3;
      int kc  = (c & 7) << 3;
      *(bf16x8*)&As[row*72 + kc] = *(const bf16x8*)&attnb[(size_t)(m0+row)*DIM + k0 + kc];
      *(bf16x8*)&Bs[row*72 + kc] = *(const bf16x8*)&wo   [(size_t)(n0+row)*DIM + k0 + kc];
    }
    __syncthreads();
#pragma unroll
    for (int kk = 0; kk < 2; ++kk) {
      const int ko = kk*32 + quad*8;
      bf16x8 af[4], bfr[4];
#pragma unroll
      for (int f = 0; f < 4; ++f) {
        af[f]  = *(const bf16x8*)&As[(wm + f*16 + l16)*72 + ko];
        bfr[f] = *(const bf16x8*)&Bs[(wn + f*16 + l16)*72 + ko];
      }
#pragma unroll
      for (int fm = 0; fm < 4; ++fm)
#pragma unroll
        for (int fn = 0; fn < 4; ++fn)
          acc[fm][fn] = MFMA16(af[fm], bfr[fn], acc[fm][fn]);
    }
    __syncthreads();
  }

#pragma unroll
  for (int fm = 0; fm < 4; ++fm) {
#pragma unroll
    for (int fn = 0; fn < 4; ++fn) {
      const int col  = n0 + wn + fn*16 + l16;
      const float bc = bo[col];
#pragma unroll
      for (int r = 0; r < 4; ++r) {
        const int row = m0 + wm + fm*16 + quad*4 + r;
        out[(size_t)row*DIM + col] = acc[fm][fn][r] + bc;
      }
    }
  }
}

// ---------------------------------------------------------------------------
// Flash attention v2: 1D grid of 512 blocks (balanced causal mapping),
// 4 independent waves/block, 32 q-rows per wave, 64-key tiles.
// Per tile: 16 QK MFMAs + 16 PV MFMAs, V prefetched under softmax.
// No __syncthreads anywhere (P transpose LDS is per-wave).
// ---------------------------------------------------------------------------
__global__ __launch_bounds__(256) void flash_attn(
    const __bf16* __restrict__ Qb, const __bf16* __restrict__ Kb,
    const __bf16* __restrict__ Vt, __bf16* __restrict__ attnb)
{
  const int n  = blockIdx.x;
  const int j  = n & 15, bh = n >> 4;
  // balanced causal mapping: consecutive j pairs sum to constant work
  const int qt = (j & 1) ? (15 - (j >> 1)) : (j >> 1);
  const int b  = bh >> 3, h = bh & 7;
  const int tid = threadIdx.x;
  const int w   = tid >> 6, lane = tid & 63, quad = lane >> 4, l16 = lane & 15;
  const int q0  = qt * 128 + w * 32;           // 32 q-rows per wave

  const __bf16* Qp = Qb + (size_t)bh * SEQ * DH;   // [s][dh]
  const __bf16* Kp = Kb + (size_t)bh * SEQ * DH;   // [s][dh]
  const __bf16* Vp = Vt + (size_t)bh * DH * SEQ;   // [dh][s]

  __shared__ __bf16 Plds[4][32*72];            // per-wave P transpose patch
  __bf16* Pw = Plds[w];

  // Q fragments: 2 m-frags x 2 k-chunks
  bf16x8 qf[2][2];
#pragma unroll
  for (int mf = 0; mf < 2; ++mf)
#pragma unroll
    for (int kk = 0; kk < 2; ++kk)
      qf[mf][kk] = *(const bf16x8*)&Qp[(size_t)(q0 + mf*16 + l16)*DH + kk*32 + quad*8];

  f32x4 of[2][4] = {};
  float m_[2][4], l_[2][4];
#pragma unroll
  for (int mf = 0; mf < 2; ++mf)
#pragma unroll
    for (int r = 0; r < 4; ++r) { m_[mf][r] = -1e30f; l_[mf][r] = 0.f; }

  const int ktiles = (q0 + 31) / 64 + 1;       // k0max <= q0 guaranteed
  for (int kt = 0; kt < ktiles; ++kt) {
    const int k0 = kt * 64;

    // ---- load all 8 K frags, then QK^T (16 MFMAs) ----
    bf16x8 kf[4][2];
#pragma unroll
    for (int fn = 0; fn < 4; ++fn)
#pragma unroll
      for (int kk = 0; kk < 2; ++kk)
        kf[fn][kk] = *(const bf16x8*)&Kp[(size_t)(k0 + fn*16 + l16)*DH + kk*32 + quad*8];

    f32x4 sf[2][4] = {};
#pragma unroll
    for (int mf = 0; mf < 2; ++mf)
#pragma unroll
      for (int fn = 0; fn < 4; ++fn) {
        sf[mf][fn] = MFMA16(qf[mf][0], kf[fn][0], sf[mf][fn]);
        sf[mf][fn] = MFMA16(qf[mf][1], kf[fn][1], sf[mf][fn]);
      }

    // ---- prefetch V frags (latency hides under softmax) ----
    bf16x8 vf[4][2];
#pragma unroll
    for (int nd = 0; nd < 4; ++nd)
#pragma unroll
      for (int kq = 0; kq < 2; ++kq)
        vf[nd][kq] = *(const bf16x8*)&Vp[(size_t)(nd*16 + l16)*SEQ + k0 + kq*32 + quad*8];

    // ---- scale + causal mask ----
    const bool need_mask = (k0 + 63 > q0);
#pragma unroll
    for (int mf = 0; mf < 2; ++mf)
#pragma unroll
      for (int fn = 0; fn < 4; ++fn) {
        const int col = k0 + fn*16 + l16;
#pragma unroll
        for (int r = 0; r < 4; ++r) {
          float v = sf[mf][fn][r] * 0.125f;
          if (need_mask) {
            const int row = q0 + mf*16 + quad*4 + r;
            if (col > row) v = -1e30f;
          }
          sf[mf][fn][r] = v;
        }
      }

    // ---- online softmax over 8 (mf,r) rows ----
    float rmax[2][4];
#pragma unroll
    for (int mf = 0; mf < 2; ++mf)
#pragma unroll
      for (int r = 0; r < 4; ++r)
        rmax[mf][r] = fmaxf(fmaxf(sf[mf][0][r], sf[mf][1][r]),
                            fmaxf(sf[mf][2][r], sf[mf][3][r]));
#pragma unroll
    for (int d = 1; d < 16; d <<= 1)
#pragma unroll
      for (int mf = 0; mf < 2; ++mf)
#pragma unroll
        for (int r = 0; r < 4; ++r)
          rmax[mf][r] = fmaxf(rmax[mf][r], __shfl_xor(rmax[mf][r], d));

#pragma unroll
    for (int mf = 0; mf < 2; ++mf)
#pragma unroll
      for (int r = 0; r < 4; ++r) {
        const float mn = fmaxf(m_[mf][r], rmax[mf][r]);
        const float al = __expf(m_[mf][r] - mn);
        m_[mf][r] = mn;
        l_[mf][r] *= al;
#pragma unroll
        for (int nd = 0; nd < 4; ++nd)
          of[mf][nd][r] *= al;
      }

#pragma unroll
    for (int mf = 0; mf < 2; ++mf)
#pragma unroll
      for (int fn = 0; fn < 4; ++fn)
#pragma unroll
        for (int r = 0; r < 4; ++r)
          sf[mf][fn][r] = __expf(sf[mf][fn][r] - m_[mf][r]);

    float rsum[2][4];
#pragma unroll
    for (int mf = 0; mf < 2; ++mf)
#pragma unroll
      for (int r = 0; r < 4; ++r)
        rsum[mf][r] = (sf[mf][0][r] + sf[mf][1][r]) + (sf[mf][2][r] + sf[mf][3][r]);
#pragma unroll
    for (int d = 1; d < 16; d <<= 1)
#pragma unroll
      for (int mf = 0; mf < 2; ++mf)
#pragma unroll
        for (int r = 0; r < 4; ++r)
          rsum[mf][r] += __shfl_xor(rsum[mf][r], d);
#pragma unroll
    for (int mf = 0; mf < 2; ++mf)
#pragma unroll
      for (int r = 0; r < 4; ++r)
        l_[mf][r] += rsum[mf][r];

    // ---- P: C-layout -> per-wave LDS -> A-layout ----
#pragma unroll
    for (int mf = 0; mf < 2; ++mf)
#pragma unroll
      for (int fn = 0; fn < 4; ++fn)
#pragma unroll
        for (int r = 0; r < 4; ++r)
          Pw[(mf*16 + quad*4 + r)*72 + fn*16 + l16] = (__bf16)sf[mf][fn][r];

    bf16x8 pa[2][2];
#pragma unroll
    for (int mf = 0; mf < 2; ++mf)
#pragma unroll
      for (int kq = 0; kq < 2; ++kq)
        pa[mf][kq] = *(const bf16x8*)&Pw[(mf*16 + l16)*72 + kq*32 + quad*8];

    // ---- O += P V (16 MFMAs) ----
#pragma unroll
    for (int mf = 0; mf < 2; ++mf)
#pragma unroll
      for (int nd = 0; nd < 4; ++nd) {
        of[mf][nd] = MFMA16(pa[mf][0], vf[nd][0], of[mf][nd]);
        of[mf][nd] = MFMA16(pa[mf][1], vf[nd][1], of[mf][nd]);
      }
  }

  // ---- normalize + store merged-head layout [B, S, H*Dh] ----
#pragma unroll
  for (int mf = 0; mf < 2; ++mf)
#pragma unroll
    for (int r = 0; r < 4; ++r)
      l_[mf][r] = 1.0f / l_[mf][r];
#pragma unroll
  for (int mf = 0; mf < 2; ++mf)
#pragma unroll
    for (int nd = 0; nd < 4; ++nd) {
      const int dh = nd*16 + l16;
#pragma unroll
      for (int r = 0; r < 4; ++r) {
        const int q = q0 + mf*16 + quad*4 + r;
        attnb[((size_t)b*SEQ + q)*DIM + h*DH + dh] = (__bf16)(of[mf][nd][r] * l_[mf][r]);
      }
    }
}

// ---------------------------------------------------------------------------
extern "C" void kernel_launch(void* const* d_in, const int* in_sizes, int n_in,
                              void* d_out, int out_size, void* d_ws, size_t ws_size,
                              hipStream_t stream) {
  const float* x  = (const float*)d_in[0];
  // d_in[1] = causal mask, unused (causality computed analytically)
  const float* Wq = (const float*)d_in[2];
  const float* bq = (const float*)d_in[3];
  const float* Wk = (const float*)d_in[4];
  const float* bk = (const float*)d_in[5];
  const float* Wv = (const float*)d_in[6];
  const float* bv = (const float*)d_in[7];
  const float* Wo = (const float*)d_in[8];
  const float* bo = (const float*)d_in[9];
  float* out = (float*)d_out;

  // workspace carve-up (bf16 elements), total ~44 MB
  __bf16* xb    = (__bf16*)d_ws;
  __bf16* wq    = xb + (size_t)NTOK*DIM;
  __bf16* wk    = wq + DIM*DIM;
  __bf16* wv    = wk + DIM*DIM;
  __bf16* wo    = wv + DIM*DIM;
  __bf16* Qb    = wo + DIM*DIM;
  __bf16* Kb    = Qb + (size_t)NTOK*DIM;
  __bf16* Vt    = Kb + (size_t)NTOK*DIM;
  __bf16* attnb = Vt + (size_t)NTOK*DIM;

  // converts
  cvt_f32_bf16<<<(NTOK*DIM/8)/256, 256, 0, stream>>>(x,  xb, NTOK*DIM/8);
  cvt_f32_bf16<<<(DIM*DIM/8)/256,  256, 0, stream>>>(Wq, wq, DIM*DIM/8);
  cvt_f32_bf16<<<(DIM*DIM/8)/256,  256, 0, stream>>>(Wk, wk, DIM*DIM/8);
  cvt_f32_bf16<<<(DIM*DIM/8)/256,  256, 0, stream>>>(Wv, wv, DIM*DIM/8);
  cvt_f32_bf16<<<(DIM*DIM/8)/256,  256, 0, stream>>>(Wo, wo, DIM*DIM/8);

  // Q/K/V projections
  gemm_qkv<<<dim3(NTOK/128, DIM/128, 3), 256, 0, stream>>>(
      xb, wq, wk, wv, bq, bk, bv, Qb, Kb, Vt);

  // flash attention (1D balanced grid)
  flash_attn<<<512, 256, 0, stream>>>(Qb, Kb, Vt, attnb);

  // output projection
  gemm_out<<<dim3(NTOK/128, DIM/128), 256, 0, stream>>>(attnb, wo, bo, out);
}

// Round 3
// 211.257 us; speedup vs baseline: 1.7355x; 1.2327x over previous
//
#include <hip/hip_runtime.h>
#include <hip/hip_bf16.h>

// Problem constants (B=4, S=2048, D=512, H=8, Dh=64)
#define BATCH 4
#define SEQ   2048
#define DIM   512
#define NH    8
#define DH    64
#define NTOK  (BATCH*SEQ)        // 8192

typedef __bf16 bf16x8 __attribute__((ext_vector_type(8)));
typedef float  f32x4  __attribute__((ext_vector_type(4)));

#define MFMA16(a,b,c) __builtin_amdgcn_mfma_f32_16x16x32_bf16((a),(b),(c),0,0,0)

// ---------------------------------------------------------------------------
// fp32 -> bf16 convert, 8 elems/thread
// ---------------------------------------------------------------------------
__global__ __launch_bounds__(256) void cvt_f32_bf16(const float* __restrict__ src,
                                                    __bf16* __restrict__ dst, int n8) {
  int i = blockIdx.x * blockDim.x + threadIdx.x;
  if (i >= n8) return;
  const float4* s = (const float4*)src;
  float4 a = s[2*i], b = s[2*i+1];
  bf16x8 o;
  o[0] = (__bf16)a.x; o[1] = (__bf16)a.y; o[2] = (__bf16)a.z; o[3] = (__bf16)a.w;
  o[4] = (__bf16)b.x; o[5] = (__bf16)b.y; o[6] = (__bf16)b.z; o[7] = (__bf16)b.w;
  *(bf16x8*)&dst[8*i] = o;
}

// all four 512x512 weights in one launch (saves 3 kernel-launch gaps)
__global__ __launch_bounds__(256) void cvt_weights(
    const float* __restrict__ s0, const float* __restrict__ s1,
    const float* __restrict__ s2, const float* __restrict__ s3,
    __bf16* __restrict__ o0, __bf16* __restrict__ o1,
    __bf16* __restrict__ o2, __bf16* __restrict__ o3) {
  int i = blockIdx.x * blockDim.x + threadIdx.x;   // 4 * 32768 chunks of 8
  const int which = i >> 15, off = i & 32767;
  const float* src = (which == 0) ? s0 : (which == 1) ? s1 : (which == 2) ? s2 : s3;
  __bf16* dst      = (which == 0) ? o0 : (which == 1) ? o1 : (which == 2) ? o2 : o3;
  const float4* s = (const float4*)src;
  float4 a = s[2*off], b = s[2*off+1];
  bf16x8 o;
  o[0] = (__bf16)a.x; o[1] = (__bf16)a.y; o[2] = (__bf16)a.z; o[3] = (__bf16)a.w;
  o[4] = (__bf16)b.x; o[5] = (__bf16)b.y; o[6] = (__bf16)b.z; o[7] = (__bf16)b.w;
  *(bf16x8*)&dst[8*off] = o;
}

// ---------------------------------------------------------------------------
// NT GEMM 128x128 tile: C[i,j] = sum_k A[i,k]*W[j,k] + bias[j]
// z = 0/1/2 -> Q / K / V projection; Q,K stored [B,H,S,Dh]; V stored [B,H,Dh,S]
// ---------------------------------------------------------------------------
__global__ __launch_bounds__(256) void gemm_qkv(
    const __bf16* __restrict__ xb,
    const __bf16* __restrict__ wq, const __bf16* __restrict__ wk,
    const __bf16* __restrict__ wv,
    const float* __restrict__ bq, const float* __restrict__ bk,
    const float* __restrict__ bv,
    __bf16* __restrict__ Qb, __bf16* __restrict__ Kb, __bf16* __restrict__ Vt)
{
  const int z = blockIdx.z;
  const __bf16* W    = (z == 0) ? wq : (z == 1) ? wk : wv;
  const float*  bias = (z == 0) ? bq : (z == 1) ? bk : bv;

  __shared__ __bf16 As[128*72];   // +8 pad: 2-way LDS conflict only (free)
  __shared__ __bf16 Bs[128*72];

  const int tid  = threadIdx.x;
  const int m0   = blockIdx.x * 128, n0 = blockIdx.y * 128;
  const int w    = tid >> 6, lane = tid & 63, quad = lane >> 4, l16 = lane & 15;
  const int wm   = (w >> 1) * 64, wn = (w & 1) * 64;

  f32x4 acc[4][4] = {};

  for (int k0 = 0; k0 < DIM; k0 += 64) {
#pragma unroll
    for (int i = 0; i < 4; ++i) {
      int c   = tid + i * 256;       // 1024 chunks of 8 bf16
      int row = c >> 3;
      int kc  = (c & 7) << 3;
      *(bf16x8*)&As[row*72 + kc] = *(const bf16x8*)&xb[(size_t)(m0+row)*DIM + k0 + kc];
      *(bf16x8*)&Bs[row*72 + kc] = *(const bf16x8*)&W [(size_t)(n0+row)*DIM + k0 + kc];
    }
    __syncthreads();
#pragma unroll
    for (int kk = 0; kk < 2; ++kk) {
      const int ko = kk*32 + quad*8;
      bf16x8 af[4], bfr[4];
#pragma unroll
      for (int f = 0; f < 4; ++f) {
        af[f]  = *(const bf16x8*)&As[(wm + f*16 + l16)*72 + ko];
        bfr[f] = *(const bf16x8*)&Bs[(wn + f*16 + l16)*72 + ko];
      }
#pragma unroll
      for (int fm = 0; fm < 4; ++fm)
#pragma unroll
        for (int fn = 0; fn < 4; ++fn)
          acc[fm][fn] = MFMA16(af[fm], bfr[fn], acc[fm][fn]);
    }
    __syncthreads();
  }

  // epilogue: C row = m0+wm+fm*16+quad*4+r ; col = n0+wn+fn*16+l16
#pragma unroll
  for (int fm = 0; fm < 4; ++fm) {
#pragma unroll
    for (int fn = 0; fn < 4; ++fn) {
      const int col  = n0 + wn + fn*16 + l16;
      const float bc = bias[col];
      const int h = col >> 6, dh = col & 63;
#pragma unroll
      for (int r = 0; r < 4; ++r) {
        const int row = m0 + wm + fm*16 + quad*4 + r;
        const int b = row >> 11, s = row & 2047;
        const float v = acc[fm][fn][r] + bc;
        if (z == 2) {
          Vt[((size_t)(b*NH + h)*DH + dh)*SEQ + s] = (__bf16)v;
        } else {
          __bf16* O = (z == 0) ? Qb : Kb;
          O[((size_t)(b*NH + h)*SEQ + s)*DH + dh] = (__bf16)v;
        }
      }
    }
  }
}

// ---------------------------------------------------------------------------
// Output projection: out[i,j] = sum_k attn[i,k]*Wo[j,k] + bo[j]  (fp32 out)
// ---------------------------------------------------------------------------
__global__ __launch_bounds__(256) void gemm_out(
    const __bf16* __restrict__ attnb, const __bf16* __restrict__ wo,
    const float* __restrict__ bo, float* __restrict__ out)
{
  __shared__ __bf16 As[128*72];
  __shared__ __bf16 Bs[128*72];

  const int tid = threadIdx.x;
  const int m0  = blockIdx.x * 128, n0 = blockIdx.y * 128;
  const int w   = tid >> 6, lane = tid & 63, quad = lane >> 4, l16 = lane & 15;
  const int wm  = (w >> 1) * 64, wn = (w & 1) * 64;

  f32x4 acc[4][4] = {};

  for (int k0 = 0; k0 < DIM; k0 += 64) {
#pragma unroll
    for (int i = 0; i < 4; ++i) {
      int c   = tid + i * 256;
      int row = c >> 3;
      int kc  = (c & 7) << 3;
      *(bf16x8*)&As[row*72 + kc] = *(const bf16x8*)&attnb[(size_t)(m0+row)*DIM + k0 + kc];
      *(bf16x8*)&Bs[row*72 + kc] = *(const bf16x8*)&wo   [(size_t)(n0+row)*DIM + k0 + kc];
    }
    __syncthreads();
#pragma unroll
    for (int kk = 0; kk < 2; ++kk) {
      const int ko = kk*32 + quad*8;
      bf16x8 af[4], bfr[4];
#pragma unroll
      for (int f = 0; f < 4; ++f) {
        af[f]  = *(const bf16x8*)&As[(wm + f*16 + l16)*72 + ko];
        bfr[f] = *(const bf16x8*)&Bs[(wn + f*16 + l16)*72 + ko];
      }
#pragma unroll
      for (int fm = 0; fm < 4; ++fm)
#pragma unroll
        for (int fn = 0; fn < 4; ++fn)
          acc[fm][fn] = MFMA16(af[fm], bfr[fn], acc[fm][fn]);
    }
    __syncthreads();
  }

#pragma unroll
  for (int fm = 0; fm < 4; ++fm) {
#pragma unroll
    for (int fn = 0; fn < 4; ++fn) {
      const int col  = n0 + wn + fn*16 + l16;
      const float bc = bo[col];
#pragma unroll
      for (int r = 0; r < 4; ++r) {
        const int row = m0 + wm + fm*16 + quad*4 + r;
        out[(size_t)row*DIM + col] = acc[fm][fn][r] + bc;
      }
    }
  }
}

// ---------------------------------------------------------------------------
// Flash attention v3: 2048 one-wave blocks (64 thr), 32 q-rows/wave,
// 64-key tiles, heavy-first dispatch (dynamic LPT balance via HW dispatcher),
// K register double-buffer (ping-pong macro — literal indices, no spills),
// V issued early in-tile (latency hides under softmax). No barriers.
// ---------------------------------------------------------------------------
__global__ __launch_bounds__(64) void flash_attn(
    const __bf16* __restrict__ Qb, const __bf16* __restrict__ Kb,
    const __bf16* __restrict__ Vt, __bf16* __restrict__ attnb)
{
  const int idx = blockIdx.x;
  const int bh  = idx & 31;                    // spread heads across XCDs
  const int t   = 63 - (idx >> 5);             // heavy q-tiles dispatch first
  const int b   = bh >> 3, h = bh & 7;
  const int lane = threadIdx.x & 63, quad = lane >> 4, l16 = lane & 15;
  const int q0  = t * 32;

  const __bf16* Qp = Qb + (size_t)bh * SEQ * DH;   // [s][dh]
  const __bf16* Kp = Kb + (size_t)bh * SEQ * DH;   // [s][dh]
  const __bf16* Vp = Vt + (size_t)bh * DH * SEQ;   // [dh][s]

  __shared__ __bf16 Pw[32*72];                 // P transpose patch (one wave)

  // Q fragments, pre-scaled by 1/sqrt(Dh)=0.125 (exact in bf16)
  bf16x8 qf[2][2];
#pragma unroll
  for (int mf = 0; mf < 2; ++mf)
#pragma unroll
    for (int kk = 0; kk < 2; ++kk) {
      bf16x8 q = *(const bf16x8*)&Qp[(size_t)(q0 + mf*16 + l16)*DH + kk*32 + quad*8];
#pragma unroll
      for (int j = 0; j < 8; ++j) q[j] = (__bf16)((float)q[j] * 0.125f);
      qf[mf][kk] = q;
    }

  f32x4 of[2][4] = {};
  float m_[2][4], l_[2][4];
#pragma unroll
  for (int mf = 0; mf < 2; ++mf)
#pragma unroll
    for (int r = 0; r < 4; ++r) { m_[mf][r] = -1e30f; l_[mf][r] = 0.f; }

  const int ktiles = (q0 >> 6) + 1;            // covers keys [0, q0+32)

  bf16x8 kfA[4][2], kfB[4][2];
  // prologue: K tile 0 into buffer A
#pragma unroll
  for (int fn = 0; fn < 4; ++fn)
#pragma unroll
    for (int kk = 0; kk < 2; ++kk)
      kfA[fn][kk] = *(const bf16x8*)&Kp[(size_t)(fn*16 + l16)*DH + kk*32 + quad*8];

#define TILE_STEP(KC, KN, KT)                                                  \
  {                                                                            \
    const int k0 = (KT) * 64;                                                  \
    /* V for this tile — issued first, consumed after softmax */               \
    bf16x8 vf[4][2];                                                           \
    _Pragma("unroll")                                                          \
    for (int nd = 0; nd < 4; ++nd)                                             \
      _Pragma("unroll")                                                        \
      for (int kq = 0; kq < 2; ++kq)                                           \
        vf[nd][kq] = *(const bf16x8*)&Vp[(size_t)(nd*16 + l16)*SEQ + k0 +      \
                                         kq*32 + quad*8];                      \
    /* prefetch next K tile into the other buffer */                           \
    {                                                                          \
      const int kn0 = ((KT) + 1 < ktiles) ? k0 + 64 : 0;                       \
      _Pragma("unroll")                                                        \
      for (int fn = 0; fn < 4; ++fn)                                           \
        _Pragma("unroll")                                                      \
        for (int kk = 0; kk < 2; ++kk)                                         \
          KN[fn][kk] = *(const bf16x8*)&Kp[(size_t)(kn0 + fn*16 + l16)*DH +    \
                                           kk*32 + quad*8];                    \
    }                                                                          \
    /* QK^T (16 MFMAs), Q pre-scaled */                                        \
    f32x4 sf[2][4] = {};                                                       \
    _Pragma("unroll")                                                          \
    for (int mf = 0; mf < 2; ++mf)                                             \
      _Pragma("unroll")                                                        \
      for (int fn = 0; fn < 4; ++fn) {                                         \
        sf[mf][fn] = MFMA16(qf[mf][0], KC[fn][0], sf[mf][fn]);                 \
        sf[mf][fn] = MFMA16(qf[mf][1], KC[fn][1], sf[mf][fn]);                 \
      }                                                                        \
    /* causal mask (only the last 1-2 tiles need it) */                        \
    if (k0 + 63 > q0) {                                                        \
      _Pragma("unroll")                                                        \
      for (int mf = 0; mf < 2; ++mf)                                           \
        _Pragma("unroll")                                                      \
        for (int fn = 0; fn < 4; ++fn) {                                       \
          const int col = k0 + fn*16 + l16;                                    \
          _Pragma("unroll")                                                    \
          for (int r = 0; r < 4; ++r) {                                        \
            const int row = q0 + mf*16 + quad*4 + r;                           \
            if (col > row) sf[mf][fn][r] = -1e30f;                             \
          }                                                                    \
        }                                                                      \
    }                                                                          \
    /* online softmax over 8 (mf,r) rows */                                    \
    float rmax[2][4];                                                          \
    _Pragma("unroll")                                                          \
    for (int mf = 0; mf < 2; ++mf)                                             \
      _Pragma("unroll")                                                        \
      for (int r = 0; r < 4; ++r)                                              \
        rmax[mf][r] = fmaxf(fmaxf(sf[mf][0][r], sf[mf][1][r]),                 \
                            fmaxf(sf[mf][2][r], sf[mf][3][r]));                \
    _Pragma("unroll")                                                          \
    for (int d = 1; d < 16; d <<= 1)                                           \
      _Pragma("unroll")                                                        \
      for (int mf = 0; mf < 2; ++mf)                                           \
        _Pragma("unroll")                                                      \
        for (int r = 0; r < 4; ++r)                                            \
          rmax[mf][r] = fmaxf(rmax[mf][r], __shfl_xor(rmax[mf][r], d));        \
    _Pragma("unroll")                                                          \
    for (int mf = 0; mf < 2; ++mf)                                             \
      _Pragma("unroll")                                                        \
      for (int r = 0; r < 4; ++r) {                                            \
        const float mn = fmaxf(m_[mf][r], rmax[mf][r]);                        \
        const float al = __expf(m_[mf][r] - mn);                               \
        m_[mf][r] = mn;                                                        \
        l_[mf][r] *= al;                                                       \
        _Pragma("unroll")                                                      \
        for (int nd = 0; nd < 4; ++nd) of[mf][nd][r] *= al;                    \
      }                                                                        \
    _Pragma("unroll")                                                          \
    for (int mf = 0; mf < 2; ++mf)                                             \
      _Pragma("unroll")                                                        \
      for (int fn = 0; fn < 4; ++fn)                                           \
        _Pragma("unroll")                                                      \
        for (int r = 0; r < 4; ++r)                                            \
          sf[mf][fn][r] = __expf(sf[mf][fn][r] - m_[mf][r]);                   \
    float rsum[2][4];                                                          \
    _Pragma("unroll")                                                          \
    for (int mf = 0; mf < 2; ++mf)                                             \
      _Pragma("unroll")                                                        \
      for (int r = 0; r < 4; ++r)                                              \
        rsum[mf][r] = (sf[mf][0][r] + sf[mf][1][r]) +                          \
                      (sf[mf][2][r] + sf[mf][3][r]);                           \
    _Pragma("unroll")                                                          \
    for (int d = 1; d < 16; d <<= 1)                                           \
      _Pragma("unroll")                                                        \
      for (int mf = 0; mf < 2; ++mf)                                           \
        _Pragma("unroll")                                                      \
        for (int r = 0; r < 4; ++r)                                            \
          rsum[mf][r] += __shfl_xor(rsum[mf][r], d);                           \
    _Pragma("unroll")                                                          \
    for (int mf = 0; mf < 2; ++mf)                                             \
      _Pragma("unroll")                                                        \
      for (int r = 0; r < 4; ++r) l_[mf][r] += rsum[mf][r];                    \
    /* P: C-layout -> LDS -> A-layout */                                       \
    _Pragma("unroll")                                                          \
    for (int mf = 0; mf < 2; ++mf)                                             \
      _Pragma("unroll")                                                        \
      for (int fn = 0; fn < 4; ++fn)                                           \
        _Pragma("unroll")                                                      \
        for (int r = 0; r < 4; ++r)                                            \
          Pw[(mf*16 + quad*4 + r)*72 + fn*16 + l16] = (__bf16)sf[mf][fn][r];   \
    bf16x8 pa[2][2];                                                           \
    _Pragma("unroll")                                                          \
    for (int mf = 0; mf < 2; ++mf)                                             \
      _Pragma("unroll")                                                        \
      for (int kq = 0; kq < 2; ++kq)                                           \
        pa[mf][kq] = *(const bf16x8*)&Pw[(mf*16 + l16)*72 + kq*32 + quad*8];   \
    /* O += P V (16 MFMAs) */                                                  \
    _Pragma("unroll")                                                          \
    for (int mf = 0; mf < 2; ++mf)                                             \
      _Pragma("unroll")                                                        \
      for (int nd = 0; nd < 4; ++nd) {                                         \
        of[mf][nd] = MFMA16(pa[mf][0], vf[nd][0], of[mf][nd]);                 \
        of[mf][nd] = MFMA16(pa[mf][1], vf[nd][1], of[mf][nd]);                 \
      }                                                                        \
  }

  for (int kt = 0; kt < ktiles; kt += 2) {
    TILE_STEP(kfA, kfB, kt);
    if (kt + 1 < ktiles) TILE_STEP(kfB, kfA, kt + 1);
  }
#undef TILE_STEP

  // ---- normalize + store merged-head layout [B, S, H*Dh] ----
#pragma unroll
  for (int mf = 0; mf < 2; ++mf)
#pragma unroll
    for (int r = 0; r < 4; ++r)
      l_[mf][r] = 1.0f / l_[mf][r];
#pragma unroll
  for (int mf = 0; mf < 2; ++mf)
#pragma unroll
    for (int nd = 0; nd < 4; ++nd) {
      const int dh = nd*16 + l16;
#pragma unroll
      for (int r = 0; r < 4; ++r) {
        const int q = q0 + mf*16 + quad*4 + r;
        attnb[((size_t)b*SEQ + q)*DIM + h*DH + dh] = (__bf16)(of[mf][nd][r] * l_[mf][r]);
      }
    }
}

// ---------------------------------------------------------------------------
extern "C" void kernel_launch(void* const* d_in, const int* in_sizes, int n_in,
                              void* d_out, int out_size, void* d_ws, size_t ws_size,
                              hipStream_t stream) {
  const float* x  = (const float*)d_in[0];
  // d_in[1] = causal mask, unused (causality computed analytically)
  const float* Wq = (const float*)d_in[2];
  const float* bq = (const float*)d_in[3];
  const float* Wk = (const float*)d_in[4];
  const float* bk = (const float*)d_in[5];
  const float* Wv = (const float*)d_in[6];
  const float* bv = (const float*)d_in[7];
  const float* Wo = (const float*)d_in[8];
  const float* bo = (const float*)d_in[9];
  float* out = (float*)d_out;

  // workspace carve-up (bf16 elements), total ~44 MB
  __bf16* xb    = (__bf16*)d_ws;
  __bf16* wq    = xb + (size_t)NTOK*DIM;
  __bf16* wk    = wq + DIM*DIM;
  __bf16* wv    = wk + DIM*DIM;
  __bf16* wo    = wv + DIM*DIM;
  __bf16* Qb    = wo + DIM*DIM;
  __bf16* Kb    = Qb + (size_t)NTOK*DIM;
  __bf16* Vt    = Kb + (size_t)NTOK*DIM;
  __bf16* attnb = Vt + (size_t)NTOK*DIM;

  // converts (2 launches)
  cvt_f32_bf16<<<(NTOK*DIM/8)/256, 256, 0, stream>>>(x, xb, NTOK*DIM/8);
  cvt_weights<<<(4*DIM*DIM/8)/256, 256, 0, stream>>>(Wq, Wk, Wv, Wo, wq, wk, wv, wo);

  // Q/K/V projections
  gemm_qkv<<<dim3(NTOK/128, DIM/128, 3), 256, 0, stream>>>(
      xb, wq, wk, wv, bq, bk, bv, Qb, Kb, Vt);

  // flash attention (one-wave blocks, heavy-first)
  flash_attn<<<2048, 64, 0, stream>>>(Qb, Kb, Vt, attnb);

  // output projection
  gemm_out<<<dim3(NTOK/128, DIM/128), 256, 0, stream>>>(attnb, wo, bo, out);
}